// Round 2
// baseline (611.994 us; speedup 1.0000x reference)
//
#include <hip/hip_runtime.h>

#define TILE 64
#define HALO 5
#define KSIZE 11
#define IN_TILE (TILE + 2 * HALO)   // 74
#define LDS_STRIDE 76               // 74 rounded up: rows stay 16B-aligned
#define IMG 1024

__global__ __launch_bounds__(256, 4)
void conv11_tile_kernel(const float* __restrict__ x,
                        const float* __restrict__ w,
                        float* __restrict__ out) {
    __shared__ float tile[IN_TILE * LDS_STRIDE];

    const int tx = threadIdx.x & 15;   // 16 threads across
    const int ty = threadIdx.x >> 4;   // 16 threads down
    const int tile_x0 = blockIdx.x * TILE;
    const int tile_y0 = blockIdx.y * TILE;
    const int b = blockIdx.z;

    const float* xb = x + (size_t)b * IMG * IMG;

    // ---- stage 74x74 input tile (zero-padded halo) into LDS ----
    for (int i = threadIdx.x; i < IN_TILE * IN_TILE; i += 256) {
        int row = i / IN_TILE;
        int col = i - row * IN_TILE;
        int gy = tile_y0 + row - HALO;
        int gx = tile_x0 + col - HALO;
        float v = 0.0f;
        if ((unsigned)gy < IMG && (unsigned)gx < IMG)
            v = xb[gy * IMG + gx];
        tile[row * LDS_STRIDE + col] = v;
    }
    __syncthreads();

    // ---- compute 4x4 outputs per thread, sliding over 14 input rows ----
    float acc[4][4] = {};
    const int lx = tx * 4;
    const int ly = ty * 4;

    #pragma unroll
    for (int iy = 0; iy < 14; ++iy) {
        const float4* rp =
            (const float4*)&tile[(ly + iy) * LDS_STRIDE + lx];
        float4 r0 = rp[0], r1 = rp[1], r2 = rp[2], r3 = rp[3];
        float r[16] = {r0.x, r0.y, r0.z, r0.w, r1.x, r1.y, r1.z, r1.w,
                       r2.x, r2.y, r2.z, r2.w, r3.x, r3.y, r3.z, r3.w};
        #pragma unroll
        for (int oy = 0; oy < 4; ++oy) {
            const int ky = iy - oy;          // compile-time after unroll
            if (ky < 0 || ky > 10) continue; // folded at compile time
            #pragma unroll
            for (int kx = 0; kx < KSIZE; ++kx) {
                const float wv = w[ky * KSIZE + kx];  // uniform -> s_load
                acc[oy][0] = fmaf(wv, r[kx + 0], acc[oy][0]);
                acc[oy][1] = fmaf(wv, r[kx + 1], acc[oy][1]);
                acc[oy][2] = fmaf(wv, r[kx + 2], acc[oy][2]);
                acc[oy][3] = fmaf(wv, r[kx + 3], acc[oy][3]);
            }
        }
    }

    // ---- coalesced float4 stores (tiles exactly partition 1024) ----
    float* ob = out + (size_t)b * IMG * IMG;
    #pragma unroll
    for (int oy = 0; oy < 4; ++oy) {
        float4 v = make_float4(acc[oy][0], acc[oy][1], acc[oy][2], acc[oy][3]);
        *(float4*)&ob[(size_t)(tile_y0 + ly + oy) * IMG + tile_x0 + lx] = v;
    }
}

extern "C" void kernel_launch(void* const* d_in, const int* in_sizes, int n_in,
                              void* d_out, int out_size, void* d_ws, size_t ws_size,
                              hipStream_t stream) {
    const float* x = (const float*)d_in[0];
    const float* w = (const float*)d_in[1];
    float* out = (float*)d_out;

    dim3 grid(IMG / TILE, IMG / TILE, 64);   // 16 x 16 x 64
    dim3 block(256);
    conv11_tile_kernel<<<grid, block, 0, stream>>>(x, w, out);
}